// Round 7
// baseline (554.193 us; speedup 1.0000x reference)
//
#include <hip/hip_runtime.h>

#define N_NODESC 100000
#define N_EDGESC 1600000
#define E_TOTC   1700000
#define NBK      391   // dst buckets of 256 nodes
#define EPB      4096  // edges per bucket-phase block
#define NBA      416   // ceil(E_TOTC/EPB)
#define NBC      391   // ceil(N_EDGESC/EPB)

__device__ inline unsigned bf16rne(float x) {
    unsigned u = __float_as_uint(x);
    return (u + 0x7fffu + ((u >> 16) & 1u)) >> 16;
}

// ------------------------------------------------------------------
// CSR build: bucket-count -> bucket-scan -> bucket-scatter -> place
// ------------------------------------------------------------------
__global__ void k_zero(int* bcnt, int* rowptr) {
    int i = blockIdx.x * 256 + threadIdx.x;
    if (i < NBK + 1) bcnt[i] = 0;
    if (i == 0) rowptr[N_NODESC] = E_TOTC;
}

// count real edges per dst-bucket (self-loops added as constants in k_bscan)
__global__ __launch_bounds__(256) void k_cnt(const int* __restrict__ ei, int* bcnt) {
    __shared__ int hist[NBK];
    int t = threadIdx.x;
    for (int i = t; i < NBK; i += 256) hist[i] = 0;
    __syncthreads();
    int e0 = blockIdx.x * EPB;
#pragma unroll
    for (int j = 0; j < 16; ++j) {
        int e = e0 + j * 256 + t;
        if (e < N_EDGESC) atomicAdd(&hist[ei[N_EDGESC + e] >> 8], 1);
    }
    __syncthreads();
    for (int i = t; i < NBK; i += 256) {
        int c = hist[i];
        if (c) atomicAdd(&bcnt[i], c);
    }
}

// exclusive scan of 391 bucket counts (+ per-bucket self-loop constants)
__global__ void k_bscan(const int* __restrict__ bcnt, int* bucketptr, int* gcur) {
    __shared__ int sd[512];
    int t = threadIdx.x;
    int v = 0;
    if (t < NBK) v = bcnt[t] + (t == NBK - 1 ? 160 : 256);  // self-loops per bucket
    sd[t] = v;
    __syncthreads();
    for (int off = 1; off < 512; off <<= 1) {
        int x = (t >= off) ? sd[t - off] : 0;
        __syncthreads();
        sd[t] += x;
        __syncthreads();
    }
    if (t <= NBK) {
        int excl = sd[t] - v;
        bucketptr[t] = excl;
        gcur[t] = excl;
    }
}

// Phase A: scatter edges (+self loops) into bucket-contiguous tmp.
// Payload: s | (dlocal<<20).
__global__ __launch_bounds__(256) void k_bucket(const int* __restrict__ ei,
                                                int* gcur, unsigned* __restrict__ tmp) {
    __shared__ int hist[NBK];
    __shared__ int cnt[NBK];
    __shared__ int base[NBK];
    int t = threadIdx.x;
    for (int i = t; i < NBK; i += 256) { hist[i] = 0; cnt[i] = 0; }
    __syncthreads();

    int e0 = blockIdx.x * EPB;
    int ss[16], dd[16];
#pragma unroll
    for (int j = 0; j < 16; ++j) {
        int e = e0 + j * 256 + t;
        if (e < E_TOTC) {
            if (e < N_EDGESC) { ss[j] = ei[e]; dd[j] = ei[N_EDGESC + e]; }
            else { ss[j] = dd[j] = e - N_EDGESC; }
            atomicAdd(&hist[dd[j] >> 8], 1);
        } else {
            dd[j] = -1;
        }
    }
    __syncthreads();
    for (int i = t; i < NBK; i += 256) {
        int c = hist[i];
        base[i] = c > 0 ? atomicAdd(&gcur[i], c) : 0;
    }
    __syncthreads();
#pragma unroll
    for (int j = 0; j < 16; ++j) {
        if (dd[j] >= 0) {
            int b = dd[j] >> 8;
            int pos = base[b] + atomicAdd(&cnt[b], 1);
            tmp[pos] = (unsigned)ss[j] | ((unsigned)(dd[j] & 255) << 20);
        }
    }
}

// Phase B: one block per bucket. Derives per-node rowptr from tmp
// (LDS count + scan), then places edges into the final ssrc window.
__global__ __launch_bounds__(256) void k_place(const unsigned* __restrict__ tmp,
                                               const int* __restrict__ bucketptr,
                                               int* __restrict__ rowptr,
                                               int* __restrict__ ssrc) {
    __shared__ int cnt256[256];
    __shared__ int sd[256];
    __shared__ int lcur[256];
    int b = blockIdx.x;
    int t = threadIdx.x;
    int rbeg = bucketptr[b];
    int rend = bucketptr[b + 1];
    cnt256[t] = 0;
    __syncthreads();
    for (int e = rbeg + t; e < rend; e += 256)
        atomicAdd(&cnt256[tmp[e] >> 20], 1);
    __syncthreads();
    int v = cnt256[t];
    sd[t] = v;
    __syncthreads();
    for (int off = 1; off < 256; off <<= 1) {
        int x = (t >= off) ? sd[t - off] : 0;
        __syncthreads();
        sd[t] += x;
        __syncthreads();
    }
    int rp = rbeg + sd[t] - v;   // exclusive
    int nd = b * 256 + t;
    if (nd < N_NODESC) rowptr[nd] = rp;
    lcur[t] = rp;
    __syncthreads();
    for (int e = rbeg + t; e < rend; e += 256) {
        unsigned p = tmp[e];
        int pos = atomicAdd(&lcur[p >> 20], 1);
        ssrc[pos] = p & 0xFFFFFu;
    }
}

// ------------------------------------------------------------------
// Fused GEMM + attention logits + bf16 pack.
// ------------------------------------------------------------------
__global__ __launch_bounds__(256) void k_gemm_al(const float* __restrict__ A,
                                                 const float* __restrict__ W,
                                                 const float* __restrict__ a_src,
                                                 const float* __restrict__ a_dst,
                                                 unsigned* __restrict__ h_bf,
                                                 float* __restrict__ als,
                                                 float* __restrict__ ald, int M) {
    __shared__ float Xt[128][64];  // [k][m] 32 KB
    int t = threadIdx.x;
    int mbase = blockIdx.x * 64;
    {
        int r = t & 63;
        int row = mbase + r;
        if (row >= M) row = 0;  // clamp; stores are guarded
        const float4* A4 = (const float4*)A;
#pragma unroll
        for (int j = 0; j < 8; ++j) {
            int k4 = (t >> 6) + j * 4;
            float4 v = A4[(size_t)row * 32 + k4];
            int kf = k4 * 4;
            Xt[kf + 0][r] = v.x;
            Xt[kf + 1][r] = v.y;
            Xt[kf + 2][r] = v.z;
            Xt[kf + 3][r] = v.w;
        }
    }
    __syncthreads();
    int m0 = (t >> 4) * 4;
    int cg = t & 15;          // col-group: cols 8cg..8cg+7
    int n4 = cg * 2;
    float acc[4][8];
#pragma unroll
    for (int i = 0; i < 4; ++i)
#pragma unroll
        for (int j = 0; j < 8; ++j) acc[i][j] = 0.f;
    const float4* W4 = (const float4*)W;
#pragma unroll 4
    for (int k = 0; k < 128; ++k) {
        float4 b0 = W4[k * 32 + n4];
        float4 b1 = W4[k * 32 + n4 + 1];
        float4 a = *(const float4*)&Xt[k][m0];
        float av[4] = {a.x, a.y, a.z, a.w};
        float bv[8] = {b0.x, b0.y, b0.z, b0.w, b1.x, b1.y, b1.z, b1.w};
#pragma unroll
        for (int i = 0; i < 4; ++i)
#pragma unroll
            for (int j = 0; j < 8; ++j) acc[i][j] += av[i] * bv[j];
    }
    // epilogue: bf16 pack + per-head attention logits
    int head  = cg >> 1;
    int half8 = (cg & 1) * 8;
    const float4* asp = (const float4*)(a_src + head * 16 + half8);
    const float4* adp = (const float4*)(a_dst + head * 16 + half8);
    float4 as0 = asp[0], as1 = asp[1];
    float4 ad0 = adp[0], ad1 = adp[1];
    uint4* hb4 = (uint4*)h_bf;
#pragma unroll
    for (int i = 0; i < 4; ++i) {
        int m = mbase + m0 + i;
        float* a8 = acc[i];
        float ps = a8[0]*as0.x + a8[1]*as0.y + a8[2]*as0.z + a8[3]*as0.w
                 + a8[4]*as1.x + a8[5]*as1.y + a8[6]*as1.z + a8[7]*as1.w;
        float pd = a8[0]*ad0.x + a8[1]*ad0.y + a8[2]*ad0.z + a8[3]*ad0.w
                 + a8[4]*ad1.x + a8[5]*ad1.y + a8[6]*ad1.z + a8[7]*ad1.w;
        ps += __shfl_xor(ps, 1, 64);
        pd += __shfl_xor(pd, 1, 64);
        if (m < M) {
            uint4 hb;
            hb.x = bf16rne(a8[0]) | (bf16rne(a8[1]) << 16);
            hb.y = bf16rne(a8[2]) | (bf16rne(a8[3]) << 16);
            hb.z = bf16rne(a8[4]) | (bf16rne(a8[5]) << 16);
            hb.w = bf16rne(a8[6]) | (bf16rne(a8[7]) << 16);
            hb4[(size_t)m * 16 + cg] = hb;
            if ((cg & 1) == 0) {
                als[(size_t)m * 8 + head] = ps;
                ald[(size_t)m * 8 + head] = pd;
            }
        }
    }
}

// ------------------------------------------------------------------
// Weighted aggregation + softmax (no-max exp: |logit| <~6, fp32-safe).
// Feature-per-lane: one wave per node, lane f owns features 2f,2f+1
// (head f>>3) and loops over ALL edges sequentially. Zero cross-lane
// reductions (sw is carried redundantly per lane within a head group).
// Per edge: 256 B coalesced h read + broadcast 32 B als segment.
// ------------------------------------------------------------------
__global__ __launch_bounds__(256) void k_agg(const unsigned* __restrict__ h_bf,
                                             const float* __restrict__ als,
                                             const float* __restrict__ ald,
                                             const int* __restrict__ rowptr,
                                             const int* __restrict__ ssrc,
                                             const float* __restrict__ bias,
                                             float* __restrict__ out,
                                             int n, int do_relu) {
    int wid  = (blockIdx.x * blockDim.x + threadIdx.x) >> 6;
    int lane = threadIdx.x & 63;  // feature pair: cols 2*lane, 2*lane+1
    if (wid >= n) return;
    int start = rowptr[wid];
    int end   = rowptr[wid + 1];
    int hd = lane >> 3;           // head of this lane's features

    float ah = ald[(size_t)wid * 8 + hd];

    float a0 = 0.f, a1 = 0.f, c0 = 0.f, c1 = 0.f;
    float sw = 0.f, sw2 = 0.f;
#define ULO(u) __uint_as_float((u) << 16)
#define UHI(u) __uint_as_float((u) & 0xffff0000u)
    int e = start;
    for (; e + 1 < end; e += 2) {
        int s0 = ssrc[e];
        int s1 = ssrc[e + 1];
        unsigned r0 = h_bf[(size_t)s0 * 64 + lane];
        unsigned r1 = h_bf[(size_t)s1 * 64 + lane];
        float x0 = als[(size_t)s0 * 8 + hd] + ah;
        float x1 = als[(size_t)s1 * 8 + hd] + ah;
        float l0 = x0 >= 0.f ? x0 : 0.2f * x0;
        float l1 = x1 >= 0.f ? x1 : 0.2f * x1;
        float w0 = __expf(l0);
        float w1 = __expf(l1);
        sw += w0; sw2 += w1;
        a0 += w0 * ULO(r0); a1 += w0 * UHI(r0);
        c0 += w1 * ULO(r1); c1 += w1 * UHI(r1);
    }
    if (e < end) {
        int s0 = ssrc[e];
        unsigned r0 = h_bf[(size_t)s0 * 64 + lane];
        float x0 = als[(size_t)s0 * 8 + hd] + ah;
        float l0 = x0 >= 0.f ? x0 : 0.2f * x0;
        float w0 = __expf(l0);
        sw += w0;
        a0 += w0 * ULO(r0); a1 += w0 * UHI(r0);
    }
#undef ULO
#undef UHI
    a0 += c0; a1 += c1; sw += sw2;
    float ish = 1.0f / (sw + 1e-16f);
    float2 bv = ((const float2*)bias)[lane];
    float2 ov = {a0 * ish + bv.x, a1 * ish + bv.y};
    if (do_relu) {
        ov.x = fmaxf(ov.x, 0.f);
        ov.y = fmaxf(ov.y, 0.f);
    }
    ((float2*)out)[(size_t)wid * 64 + lane] = ov;
}

// ------------------------------------------------------------------
// Prediction heads
// ------------------------------------------------------------------
__global__ __launch_bounds__(256) void k_heads(const float* __restrict__ z,
                                               const int* __restrict__ tidx,
                                               const int* __restrict__ cidx,
                                               const float* __restrict__ wy1,
                                               const float* __restrict__ by1,
                                               const float* __restrict__ wy0,
                                               const float* __restrict__ by0,
                                               float* __restrict__ out, int M) {
    int wid  = (blockIdx.x * blockDim.x + threadIdx.x) >> 6;
    int lane = threadIdx.x & 63;
    if (wid >= 2 * M) return;
    int which = (wid >= M) ? 1 : 0;
    int i = wid - which * M;
    int idx = which ? cidx[i] : tidx[i];
    float2 zv = ((const float2*)(z + (size_t)idx * 128))[lane];
    float2 w1 = ((const float2*)wy1)[lane];
    float2 w0 = ((const float2*)wy0)[lane];
    float d1 = zv.x * w1.x + zv.y * w1.y;
    float d0 = zv.x * w0.x + zv.y * w0.y;
#pragma unroll
    for (int off = 32; off > 0; off >>= 1) {
        d1 += __shfl_xor(d1, off, 64);
        d0 += __shfl_xor(d0, off, 64);
    }
    if (lane == 0) {
        float y1v = d1 + by1[0]; y1v = y1v >= 0.f ? y1v : 0.01f * y1v;
        float y0v = d0 + by0[0]; y0v = y0v >= 0.f ? y0v : 0.01f * y0v;
        if (which == 0) { out[i] = y1v; out[M + i] = y0v; }
        else            { out[2 * M + i] = y0v; out[3 * M + i] = y1v; }
    }
}

// ------------------------------------------------------------------
extern "C" void kernel_launch(void* const* d_in, const int* in_sizes, int n_in,
                              void* d_out, int out_size, void* d_ws, size_t ws_size,
                              hipStream_t stream) {
    const float* x   = (const float*)d_in[0];
    const int*   ei  = (const int*)d_in[1];
    const int*   tix = (const int*)d_in[2];
    const int*   cix = (const int*)d_in[3];
    const float* W1  = (const float*)d_in[4];
    const float* as1 = (const float*)d_in[5];
    const float* ad1 = (const float*)d_in[6];
    const float* b1  = (const float*)d_in[7];
    const float* W2  = (const float*)d_in[8];
    const float* as2 = (const float*)d_in[9];
    const float* ad2 = (const float*)d_in[10];
    const float* b2  = (const float*)d_in[11];
    const float* wy1 = (const float*)d_in[12];
    const float* by1 = (const float*)d_in[13];
    const float* wy0 = (const float*)d_in[14];
    const float* by0 = (const float*)d_in[15];
    float* out = (float*)d_out;

    // workspace layout
    float* z_buf     = (float*)d_ws;                  // 12.8M f (xZ1)
    unsigned* h_bf   = (unsigned*)(z_buf + 12800000); // 6.4M u (bf16 h)
    float* als       = (float*)(h_bf + 6400000);      // 800k f
    float* ald       = als + 800000;                  // 800k f
    int* rowptr      = (int*)(ald + 800000);          // 100001
    int* bcnt        = rowptr + 100001;               // 392
    int* bucketptr   = bcnt + 392;                    // 392
    int* gcur        = bucketptr + 392;               // 392
    int* ssrc        = gcur + 392;                    // 1.7M
    unsigned* tmp    = (unsigned*)(ssrc + E_TOTC);    // 1.7M

    dim3 B(256);
    // ---- CSR build ----
    k_zero<<<2, B, 0, stream>>>(bcnt, rowptr);
    k_cnt<<<NBC, B, 0, stream>>>(ei, bcnt);
    k_bscan<<<1, dim3(512), 0, stream>>>(bcnt, bucketptr, gcur);
    k_bucket<<<NBA, B, 0, stream>>>(ei, gcur, tmp);
    k_place<<<NBK, B, 0, stream>>>(tmp, bucketptr, rowptr, ssrc);
    // ---- layer 1 ----
    k_gemm_al<<<(N_NODESC + 63) / 64, B, 0, stream>>>(x, W1, as1, ad1, h_bf, als, ald, N_NODESC);
    k_agg<<<(N_NODESC + 3) / 4, B, 0, stream>>>(h_bf, als, ald, rowptr, ssrc,
                                                b1, z_buf, N_NODESC, 1);
    // ---- layer 2 ----
    k_gemm_al<<<(N_NODESC + 63) / 64, B, 0, stream>>>(z_buf, W2, as2, ad2, h_bf, als, ald, N_NODESC);
    k_agg<<<(N_NODESC + 3) / 4, B, 0, stream>>>(h_bf, als, ald, rowptr, ssrc,
                                                b2, out + 80000, N_NODESC, 0);
    // ---- heads ----
    k_heads<<<(2 * 20000 * 64) / 256, B, 0, stream>>>(out + 80000, tix, cix,
                                                      wy1, by1, wy0, by0, out, 20000);
}